// Round 1
// baseline (61.128 us; speedup 1.0000x reference)
//
#include <hip/hip_runtime.h>
#include <hip/hip_bf16.h>
#include <float.h>

#define B 16
#define H 32
#define HKV 8
#define G 4
#define D 128
#define LMAX 2048
#define NSPLIT 8
#define CHUNK 256          // LMAX / NSPLIT
#define SCALE 0.08838834764831844f  // 1/sqrt(128)

// Kernel 1: per (b, kv-head, split) flash-decode partial.
// part_o : [B][HKV][NSPLIT][G][D]  unnormalized sum of p*V
// part_ml: [B][HKV][NSPLIT][G][2]  (m, sum_exp)
__global__ __launch_bounds__(256) void attn_partial(
    const float* __restrict__ q,
    const float* __restrict__ kin,
    const float* __restrict__ vin,
    const float* __restrict__ kc,
    const float* __restrict__ vc,
    const int*  __restrict__ slot_mapping,
    const int*  __restrict__ active_slots,
    const int*  __restrict__ context_lens,
    float* __restrict__ part_o,
    float* __restrict__ part_ml)
{
    const int tid = threadIdx.x;
    int idx = blockIdx.x;
    const int split = idx % NSPLIT; idx /= NSPLIT;
    const int h = idx % HKV;
    const int b = idx / HKV;

    const int ctx   = context_lens[b];
    const int start = split * CHUNK;
    int nvalid = ctx - start;
    if (nvalid > CHUNK) nvalid = CHUNK;

    const size_t pbase = ((size_t)(b * HKV + h) * NSPLIT + split) * G;

    if (nvalid <= 0) {
        // empty split: write zeros (ws is poisoned 0xAA, must init)
        for (int i = tid; i < G * D; i += 256) part_o[pbase * D + i] = 0.f;
        if (tid < G * 2) part_ml[pbase * 2 + tid] = (tid & 1) ? 0.f : -FLT_MAX;
        return;
    }

    __shared__ float sc[G][CHUNK];   // scores, then p
    __shared__ int   vrow[CHUNK];    // resolved V source: >=0 cache slot, <0 -> -(j+1) from vin
    __shared__ int   sm[16];

    if (tid < 16) sm[tid] = slot_mapping[tid];
    __syncthreads();

    const int grp   = tid >> 3;   // 0..31  slot-group within block
    const int lane8 = tid & 7;    // 0..7   lane within group

    // Preload this thread's q fragment (pre-scaled). d-index for load i: i*32 + lane8*4
    float4 qv[G][4];
#pragma unroll
    for (int g = 0; g < G; ++g) {
        const float* qp = q + ((size_t)(b * H + h * G + g)) * D;
#pragma unroll
        for (int i = 0; i < 4; ++i) {
            float4 t = *(const float4*)(qp + i * 32 + lane8 * 4);
            qv[g][i] = make_float4(t.x * SCALE, t.y * SCALE, t.z * SCALE, t.w * SCALE);
        }
    }

    const int iters = (nvalid + 31) >> 5;
    for (int it = 0; it < iters; ++it) {
        const int li = it * 32 + grp;       // column within chunk
        if (li < nvalid) {
            const int l = start + li;
            const int s = active_slots[b * LMAX + l];
            int ov = -1;
#pragma unroll
            for (int j = 0; j < 16; ++j)
                if (sm[j] == s) ov = j;
            const float* kb = (ov >= 0) ? (kin + ((size_t)ov * HKV + h) * D)
                                        : (kc  + ((size_t)s  * HKV + h) * D);
            float pd0 = 0.f, pd1 = 0.f, pd2 = 0.f, pd3 = 0.f;
#pragma unroll
            for (int i = 0; i < 4; ++i) {
                float4 kv = *(const float4*)(kb + i * 32 + lane8 * 4);
                pd0 += kv.x * qv[0][i].x + kv.y * qv[0][i].y + kv.z * qv[0][i].z + kv.w * qv[0][i].w;
                pd1 += kv.x * qv[1][i].x + kv.y * qv[1][i].y + kv.z * qv[1][i].z + kv.w * qv[1][i].w;
                pd2 += kv.x * qv[2][i].x + kv.y * qv[2][i].y + kv.z * qv[2][i].z + kv.w * qv[2][i].w;
                pd3 += kv.x * qv[3][i].x + kv.y * qv[3][i].y + kv.z * qv[3][i].z + kv.w * qv[3][i].w;
            }
            // reduce across the 8 lanes of the group
#pragma unroll
            for (int msk = 1; msk < 8; msk <<= 1) {
                pd0 += __shfl_xor(pd0, msk, 8);
                pd1 += __shfl_xor(pd1, msk, 8);
                pd2 += __shfl_xor(pd2, msk, 8);
                pd3 += __shfl_xor(pd3, msk, 8);
            }
            if (lane8 == 0) {
                sc[0][li] = pd0; sc[1][li] = pd1; sc[2][li] = pd2; sc[3][li] = pd3;
                vrow[li] = (ov >= 0) ? -(ov + 1) : s;
            }
        }
    }
    __syncthreads();

    // Softmax over the chunk: wave w handles g=w
    {
        const int g    = tid >> 6;   // wave index == g
        const int lane = tid & 63;
        float m = -FLT_MAX;
        for (int i = lane; i < nvalid; i += 64) m = fmaxf(m, sc[g][i]);
#pragma unroll
        for (int msk = 1; msk < 64; msk <<= 1) m = fmaxf(m, __shfl_xor(m, msk, 64));
        float sum = 0.f;
        for (int i = lane; i < nvalid; i += 64) {
            float p = __expf(sc[g][i] - m);
            sc[g][i] = p;
            sum += p;
        }
#pragma unroll
        for (int msk = 1; msk < 64; msk <<= 1) sum += __shfl_xor(sum, msk, 64);
        if (lane == 0) {
            part_ml[(pbase + g) * 2 + 0] = m;
            part_ml[(pbase + g) * 2 + 1] = sum;
        }
    }
    __syncthreads();

    // PV: thread t owns d = t&127, heads g0 = t>>7 and g0+2
    {
        const int dd = tid & 127;
        const int g0 = tid >> 7;
        float acc0 = 0.f, acc1 = 0.f;
#pragma unroll 4
        for (int i = 0; i < nvalid; ++i) {
            const int vr = vrow[i];
            const float* vb = (vr < 0) ? (vin + ((size_t)(-vr - 1) * HKV + h) * D)
                                       : (vc  + ((size_t)vr * HKV + h) * D);
            const float vval = vb[dd];
            acc0 += sc[g0][i]     * vval;
            acc1 += sc[g0 + 2][i] * vval;
        }
        part_o[(pbase + g0)     * D + dd] = acc0;
        part_o[(pbase + g0 + 2) * D + dd] = acc1;
    }
}

// Kernel 2: merge NSPLIT partials per (b, head) with log-sum-exp combine.
__global__ __launch_bounds__(128) void attn_reduce(
    const float* __restrict__ part_o,
    const float* __restrict__ part_ml,
    float* __restrict__ out)
{
    int idx = blockIdx.x;                 // [B][HKV][G]
    const int g = idx & 3;
    const int h = (idx >> 2) & 7;
    const int b = idx >> 5;
    const int d = threadIdx.x;

    const size_t base = (size_t)(b * HKV + h) * NSPLIT;

    float ms[NSPLIT], ls[NSPLIT];
    float M = -FLT_MAX;
#pragma unroll
    for (int s = 0; s < NSPLIT; ++s) {
        ms[s] = part_ml[((base + s) * G + g) * 2 + 0];
        ls[s] = part_ml[((base + s) * G + g) * 2 + 1];
        if (ls[s] > 0.f) M = fmaxf(M, ms[s]);
    }
    float L = 0.f, acc = 0.f;
#pragma unroll
    for (int s = 0; s < NSPLIT; ++s) {
        if (ls[s] > 0.f) {
            const float e = __expf(ms[s] - M);
            L += ls[s] * e;
            acc += e * part_o[((base + s) * G + g) * D + d];
        }
    }
    out[((size_t)(b * H) + h * G + g) * D + d] = acc / (L > 0.f ? L : 1.f);
}

extern "C" void kernel_launch(void* const* d_in, const int* in_sizes, int n_in,
                              void* d_out, int out_size, void* d_ws, size_t ws_size,
                              hipStream_t stream) {
    const float* q  = (const float*)d_in[0];
    const float* k  = (const float*)d_in[1];
    const float* v  = (const float*)d_in[2];
    const float* kc = (const float*)d_in[3];
    const float* vc = (const float*)d_in[4];
    const int* slot_mapping = (const int*)d_in[5];
    const int* active_slots = (const int*)d_in[6];
    const int* context_lens = (const int*)d_in[7];
    float* out = (float*)d_out;

    float* part_o  = (float*)d_ws;                                  // B*HKV*NSPLIT*G*D floats = 2 MB
    float* part_ml = part_o + (size_t)B * HKV * NSPLIT * G * D;     // B*HKV*NSPLIT*G*2 floats

    attn_partial<<<B * HKV * NSPLIT, 256, 0, stream>>>(
        q, k, v, kc, vc, slot_mapping, active_slots, context_lens, part_o, part_ml);
    attn_reduce<<<B * HKV * G, 128, 0, stream>>>(part_o, part_ml, out);
}

// Round 2
// 48.567 us; speedup vs baseline: 1.2586x; 1.2586x over previous
//
#include <hip/hip_runtime.h>
#include <hip/hip_bf16.h>
#include <float.h>

#define B 16
#define H 32
#define HKV 8
#define G 4
#define D 128
#define LMAX 2048
#define SCALE 0.08838834764831844f  // 1/sqrt(128)

// Kernel 1: per (b, kv-head, split) flash-decode partial.
// part_o : [B][HKV][NSPLIT][G][D]  unnormalized sum of p*V (only written if split non-empty)
// part_ml: [B][HKV][NSPLIT][G][2]  (m, sum_exp)  (always written)
template <int NSPLIT>
__global__ __launch_bounds__(256) void attn_partial(
    const float* __restrict__ q,
    const float* __restrict__ kin,
    const float* __restrict__ vin,
    const float* __restrict__ kc,
    const float* __restrict__ vc,
    const int*  __restrict__ slot_mapping,
    const int*  __restrict__ active_slots,
    const int*  __restrict__ context_lens,
    float* __restrict__ part_o,
    float* __restrict__ part_ml)
{
    constexpr int CHUNK = LMAX / NSPLIT;
    const int tid = threadIdx.x;
    int idx = blockIdx.x;
    const int split = idx % NSPLIT; idx /= NSPLIT;
    const int h = idx % HKV;
    const int b = idx / HKV;

    const int ctx   = context_lens[b];
    const int start = split * CHUNK;
    int nvalid = ctx - start;
    if (nvalid > CHUNK) nvalid = CHUNK;

    const size_t pbase = ((size_t)(b * HKV + h) * NSPLIT + split) * G;

    if (nvalid <= 0) {
        // empty split: mark l=0 so reduce skips part_o (which stays poisoned)
        if (tid < G * 2) part_ml[pbase * 2 + tid] = (tid & 1) ? 0.f : -FLT_MAX;
        return;
    }

    __shared__ float sc[G][CHUNK];          // scores, then p
    __shared__ const float* vptr[CHUNK];    // resolved V row pointer
    __shared__ float red[G][D];             // PV half-reduce buffer
    __shared__ int   sm[16];

    if (tid < 16) sm[tid] = slot_mapping[tid];
    __syncthreads();

    const int grp   = tid >> 3;   // 0..31  slot-group within block
    const int lane8 = tid & 7;    // 0..7   lane within group

    // Preload this thread's q fragment (pre-scaled). d-index for load i: i*32 + lane8*4
    float4 qv[G][4];
#pragma unroll
    for (int g = 0; g < G; ++g) {
        const float* qp = q + ((size_t)(b * H + h * G + g)) * D;
#pragma unroll
        for (int i = 0; i < 4; ++i) {
            float4 t = *(const float4*)(qp + i * 32 + lane8 * 4);
            qv[g][i] = make_float4(t.x * SCALE, t.y * SCALE, t.z * SCALE, t.w * SCALE);
        }
    }

    const int iters = (nvalid + 31) >> 5;
    for (int it = 0; it < iters; ++it) {
        const int li = it * 32 + grp;       // column within chunk
        if (li < nvalid) {
            const int l = start + li;
            const int s = active_slots[b * LMAX + l];
            int ov = -1;
#pragma unroll
            for (int j = 0; j < 16; ++j)
                if (sm[j] == s) ov = j;
            const float* kb = (ov >= 0) ? (kin + ((size_t)ov * HKV + h) * D)
                                        : (kc  + ((size_t)s  * HKV + h) * D);
            float pd0 = 0.f, pd1 = 0.f, pd2 = 0.f, pd3 = 0.f;
#pragma unroll
            for (int i = 0; i < 4; ++i) {
                float4 kv = *(const float4*)(kb + i * 32 + lane8 * 4);
                pd0 += kv.x * qv[0][i].x + kv.y * qv[0][i].y + kv.z * qv[0][i].z + kv.w * qv[0][i].w;
                pd1 += kv.x * qv[1][i].x + kv.y * qv[1][i].y + kv.z * qv[1][i].z + kv.w * qv[1][i].w;
                pd2 += kv.x * qv[2][i].x + kv.y * qv[2][i].y + kv.z * qv[2][i].z + kv.w * qv[2][i].w;
                pd3 += kv.x * qv[3][i].x + kv.y * qv[3][i].y + kv.z * qv[3][i].z + kv.w * qv[3][i].w;
            }
            // reduce across the 8 lanes of the group
#pragma unroll
            for (int msk = 1; msk < 8; msk <<= 1) {
                pd0 += __shfl_xor(pd0, msk, 8);
                pd1 += __shfl_xor(pd1, msk, 8);
                pd2 += __shfl_xor(pd2, msk, 8);
                pd3 += __shfl_xor(pd3, msk, 8);
            }
            if (lane8 == 0) {
                sc[0][li] = pd0; sc[1][li] = pd1; sc[2][li] = pd2; sc[3][li] = pd3;
                vptr[li] = (ov >= 0) ? (vin + ((size_t)ov * HKV + h) * D)
                                     : (vc  + ((size_t)s  * HKV + h) * D);
            }
        }
    }
    __syncthreads();

    // Softmax over the chunk: wave w handles g=w
    {
        const int g    = tid >> 6;   // wave index == g
        const int lane = tid & 63;
        float m = -FLT_MAX;
        for (int i = lane; i < nvalid; i += 64) m = fmaxf(m, sc[g][i]);
#pragma unroll
        for (int msk = 1; msk < 64; msk <<= 1) m = fmaxf(m, __shfl_xor(m, msk, 64));
        float sum = 0.f;
        for (int i = lane; i < nvalid; i += 64) {
            float p = __expf(sc[g][i] - m);
            sc[g][i] = p;
            sum += p;
        }
#pragma unroll
        for (int msk = 1; msk < 64; msk <<= 1) sum += __shfl_xor(sum, msk, 64);
        if (lane == 0) {
            part_ml[(pbase + g) * 2 + 0] = m;
            part_ml[(pbase + g) * 2 + 1] = sum;
        }
    }
    __syncthreads();

    // PV: 2 slot-halves x 128 d-threads; each thread does ALL 4 heads from one V load.
    {
        const int dd   = tid & 127;
        const int half = tid >> 7;
        float a0 = 0.f, a1 = 0.f, a2 = 0.f, a3 = 0.f;
#pragma unroll 4
        for (int i = half; i < nvalid; i += 2) {
            const float* vb = vptr[i];
            const float vval = vb[dd];
            a0 += sc[0][i] * vval;
            a1 += sc[1][i] * vval;
            a2 += sc[2][i] * vval;
            a3 += sc[3][i] * vval;
        }
        if (half == 1) {
            red[0][dd] = a0; red[1][dd] = a1; red[2][dd] = a2; red[3][dd] = a3;
        }
        __syncthreads();
        if (half == 0) {
            part_o[(pbase + 0) * D + dd] = a0 + red[0][dd];
            part_o[(pbase + 1) * D + dd] = a1 + red[1][dd];
            part_o[(pbase + 2) * D + dd] = a2 + red[2][dd];
            part_o[(pbase + 3) * D + dd] = a3 + red[3][dd];
        }
    }
}

// Kernel 2: merge nsplit partials per (b, head) with log-sum-exp combine.
__global__ __launch_bounds__(128) void attn_reduce(
    const float* __restrict__ part_o,
    const float* __restrict__ part_ml,
    float* __restrict__ out,
    int nsplit)
{
    int idx = blockIdx.x;                 // [B][HKV][G]
    const int g = idx & 3;
    const int h = (idx >> 2) & 7;
    const int b = idx >> 5;
    const int d = threadIdx.x;

    const size_t base = (size_t)(b * HKV + h) * nsplit;

    float M = -FLT_MAX;
    for (int s = 0; s < nsplit; ++s) {
        const float l = part_ml[((base + s) * G + g) * 2 + 1];
        if (l > 0.f) M = fmaxf(M, part_ml[((base + s) * G + g) * 2 + 0]);
    }
    float L = 0.f, acc = 0.f;
    for (int s = 0; s < nsplit; ++s) {
        const float l = part_ml[((base + s) * G + g) * 2 + 1];
        if (l > 0.f) {
            const float e = __expf(part_ml[((base + s) * G + g) * 2 + 0] - M);
            L += l * e;
            acc += e * part_o[((base + s) * G + g) * D + d];
        }
    }
    out[((size_t)(b * H) + h * G + g) * D + d] = acc / (L > 0.f ? L : 1.f);
}

extern "C" void kernel_launch(void* const* d_in, const int* in_sizes, int n_in,
                              void* d_out, int out_size, void* d_ws, size_t ws_size,
                              hipStream_t stream) {
    const float* q  = (const float*)d_in[0];
    const float* k  = (const float*)d_in[1];
    const float* v  = (const float*)d_in[2];
    const float* kc = (const float*)d_in[3];
    const float* vc = (const float*)d_in[4];
    const int* slot_mapping = (const int*)d_in[5];
    const int* active_slots = (const int*)d_in[6];
    const int* context_lens = (const int*)d_in[7];
    float* out = (float*)d_out;

    const size_t need16 = ((size_t)B * HKV * 16 * G * D + (size_t)B * HKV * 16 * G * 2) * sizeof(float);
    const int nsplit = (ws_size >= need16) ? 16 : 8;

    float* part_o  = (float*)d_ws;
    float* part_ml = part_o + (size_t)B * HKV * nsplit * G * D;

    if (nsplit == 16) {
        attn_partial<16><<<B * HKV * 16, 256, 0, stream>>>(
            q, k, v, kc, vc, slot_mapping, active_slots, context_lens, part_o, part_ml);
    } else {
        attn_partial<8><<<B * HKV * 8, 256, 0, stream>>>(
            q, k, v, kc, vc, slot_mapping, active_slots, context_lens, part_o, part_ml);
    }
    attn_reduce<<<B * HKV * G, 128, 0, stream>>>(part_o, part_ml, out, nsplit);
}